// Round 16
// baseline (177.353 us; speedup 1.0000x reference)
//
#include <hip/hip_runtime.h>
#include <hip/hip_bf16.h>
#include <cstdint>

// out = D^-1/2 (I+A) D^-1/2 X W + b ; N=8192, F=256, ~33 nnz/row, A symmetric.
// Stage 1 (fused): [MFMA GEMM Y=X@W -> bf16, 512 blocks at head] ||
//   [upper-triangle A-scan, one row per block. Forward list -> ell (plain,
//    single owner). Mirror edges -> 256 bucketed append queues (sequential
//    slots => dense line writes, no ell RMW scatter).]
// Stage 1.6: distribute (256 blocks): drain bucket b into its 32-row ell
//   window via LDS counters (no global atomics, window L2-resident).
// Stage 2: wave-per-row gather (R13 exact form).
// NOTE: no nontemporal hints anywhere - measured regressions (R4/R8/R15).

#define NN 8192
#define FF 256
#define ELLK 128
#define BM 64
#define BN 64
#define NGEMM ((NN / BM) * (FF / BN))   // 512 gemm blocks
#define NBUCK 256
#define BROWS (NN / NBUCK)              // 32 rows per bucket
#define BCAP  2048                      // mean load ~1050, sd ~32 -> 31 sigma

typedef short bf16x8 __attribute__((ext_vector_type(8)));
typedef float f32x4  __attribute__((ext_vector_type(4)));

__device__ __forceinline__ float bf2f(unsigned short u) {
    union { unsigned int i; float f; } c; c.i = ((unsigned int)u) << 16; return c.f;
}
__device__ __forceinline__ unsigned short f2bf(float f) {
    union { float f; unsigned int i; } c; c.f = f;
    unsigned int r = c.i + 0x7FFF + ((c.i >> 16) & 1);   // round-to-nearest-even
    return (unsigned short)(r >> 16);
}

__global__ __launch_bounds__(256) void fused_stage1(const float* __restrict__ A,
                                                    const float* __restrict__ X,
                                                    const float* __restrict__ W,
                                                    unsigned short* __restrict__ Yb,
                                                    int* __restrict__ fcnt,
                                                    unsigned short* __restrict__ ell,
                                                    int* __restrict__ bcnt,
                                                    unsigned int* __restrict__ bbuf) {
    if (blockIdx.x < NGEMM) {
        // ------------- MFMA GEMM: Y = X @ W (bf16 in, f32 acc, bf16 out) ------
        __shared__ unsigned short Xs[64][68];
        __shared__ unsigned short Wt[64][68];
        const int bid = blockIdx.x;
        const int m0 = (bid / (FF / BN)) * BM;
        const int n0 = (bid % (FF / BN)) * BN;
        const int t  = threadIdx.x;
        const int w  = t >> 6;
        const int l  = t & 63;
        const int lm = l & 15;
        const int lk = (l >> 4) << 2;
        f32x4 acc[4] = {};
        for (int kp = 0; kp < 4; ++kp) {
            const int kbase = kp * 64;
            __syncthreads();
            {   // stage X tile 64 rows x 64 k (f32 -> bf16)
                int row = t >> 2;
                #pragma unroll
                for (int q = 0; q < 4; ++q) {
                    int kq = (t & 3) * 4 + q * 16;
                    float4 v = *reinterpret_cast<const float4*>(X + (size_t)(m0 + row) * FF + kbase + kq);
                    ushort4 b = { f2bf(v.x), f2bf(v.y), f2bf(v.z), f2bf(v.w) };
                    *reinterpret_cast<ushort4*>(&Xs[row][kq]) = b;
                }
            }
            {   // stage W^T tile: Wt[n][k] from W[k][n]
                int n4 = (t & 15) * 4;
                int kk = t >> 4;
                #pragma unroll
                for (int q = 0; q < 4; ++q) {
                    int k = kk + q * 16;
                    float4 v = *reinterpret_cast<const float4*>(W + (size_t)(kbase + k) * FF + n0 + n4);
                    Wt[n4 + 0][k] = f2bf(v.x);
                    Wt[n4 + 1][k] = f2bf(v.y);
                    Wt[n4 + 2][k] = f2bf(v.z);
                    Wt[n4 + 3][k] = f2bf(v.w);
                }
            }
            __syncthreads();
            #pragma unroll
            for (int ks = 0; ks < 2; ++ks) {
                const int k0 = ks * 32;
                union { bf16x8 v; uint2 u[2]; } af;
                af.u[0] = *reinterpret_cast<const uint2*>(&Xs[w * 16 + lm][k0 + lk]);
                af.u[1] = *reinterpret_cast<const uint2*>(&Xs[w * 16 + lm][k0 + 16 + lk]);
                #pragma unroll
                for (int f = 0; f < 4; ++f) {
                    union { bf16x8 v; uint2 u[2]; } bf;
                    bf.u[0] = *reinterpret_cast<const uint2*>(&Wt[f * 16 + lm][k0 + lk]);
                    bf.u[1] = *reinterpret_cast<const uint2*>(&Wt[f * 16 + lm][k0 + 16 + lk]);
                    acc[f] = __builtin_amdgcn_mfma_f32_16x16x32_bf16(af.v, bf.v, acc[f], 0, 0, 0);
                }
            }
        }
        #pragma unroll
        for (int f = 0; f < 4; ++f) {
            #pragma unroll
            for (int r = 0; r < 4; ++r) {
                int row = m0 + w * 16 + lk + r;
                int col = n0 + f * 16 + lm;
                Yb[(size_t)row * FF + col] = f2bf(acc[f][r]);
            }
        }
    } else {
        // ------------- upper-triangle scan, ONE row per block -----------------
        __shared__ unsigned short loc[ELLK];
        __shared__ int lcnt;
        const int r = blockIdx.x - NGEMM;       // 0..8191
        if (threadIdx.x == 0) lcnt = 0;
        __syncthreads();
        const uint4* Arow = reinterpret_cast<const uint4*>(A + (size_t)r * NN);
        const int c0 = (r + 1) >> 2;            // first chunk that can hold j > r
        for (int c = c0 + threadIdx.x; c < NN / 4; c += 256) {
            uint4 v = Arow[c];
            if (v.x | v.y | v.z | v.w) {
                int b = c * 4;
                if (v.x && b + 0 > r) { int p = atomicAdd(&lcnt, 1); if (p < ELLK) loc[p] = (unsigned short)(b + 0); }
                if (v.y && b + 1 > r) { int p = atomicAdd(&lcnt, 1); if (p < ELLK) loc[p] = (unsigned short)(b + 1); }
                if (v.z && b + 2 > r) { int p = atomicAdd(&lcnt, 1); if (p < ELLK) loc[p] = (unsigned short)(b + 2); }
                if (v.w && b + 3 > r) { int p = atomicAdd(&lcnt, 1); if (p < ELLK) loc[p] = (unsigned short)(b + 3); }
            }
        }
        __syncthreads();
        const int n = lcnt < ELLK ? lcnt : ELLK;
        if (threadIdx.x == 0) fcnt[r] = n;                    // single owner
        for (int t = threadIdx.x; t < n; t += 256)            // coalesced dump
            ell[(size_t)r * ELLK + t] = loc[t];
        // mirror edges -> bucketed append queues (dense sequential writes)
        for (int t = threadIdx.x; t < n; t += 256) {
            int j = loc[t];
            int b = j >> 5;                                   // bucket = j/32
            int s = atomicAdd(&bcnt[b], 1);
            if (s < BCAP) bbuf[(size_t)b * BCAP + s] = ((unsigned int)j << 16) | (unsigned int)r;
        }
    }
}

// ---- Stage 1.6: drain bucket b into its 32-row ell window (LDS counters) ----
__global__ __launch_bounds__(256) void distribute_kernel(const int* __restrict__ fcnt,
                                                         const int* __restrict__ bcnt,
                                                         const unsigned int* __restrict__ bbuf,
                                                         int* __restrict__ cnt,
                                                         unsigned short* __restrict__ ell) {
    const int b = blockIdx.x;                 // bucket / 32-row window
    __shared__ int lcnt[BROWS];
    if (threadIdx.x < BROWS)
        lcnt[threadIdx.x] = fcnt[b * BROWS + threadIdx.x];
    __syncthreads();
    const int m = bcnt[b] < BCAP ? bcnt[b] : BCAP;
    for (int t = threadIdx.x; t < m; t += 256) {
        unsigned int e = bbuf[(size_t)b * BCAP + t];
        int j = e >> 16;
        int r = e & 0xFFFF;
        int p = atomicAdd(&lcnt[j & (BROWS - 1)], 1);
        if (p < ELLK) ell[(size_t)j * ELLK + p] = (unsigned short)r;
    }
    __syncthreads();
    if (threadIdx.x < BROWS)
        cnt[b * BROWS + threadIdx.x] = lcnt[threadIdx.x];
}

// ---- Stage 2: wave-per-row normalized aggregation over bf16 Y ---------------
__global__ __launch_bounds__(256) void spmm_kernel(const unsigned short* __restrict__ Yb,
                                                   const int* __restrict__ cnt,
                                                   const unsigned short* __restrict__ ell,
                                                   const float* __restrict__ bias,
                                                   float* __restrict__ out) {
    const int wave = threadIdx.x >> 6;
    const int lane = threadIdx.x & 63;
    const int row = blockIdx.x * 4 + wave;
    __shared__ unsigned short sidx[4][ELLK];
    __shared__ float sdj[4][ELLK];
    int c = cnt[row];
    c = c < ELLK ? c : ELLK;
    for (int t = lane; t < c; t += 64) {
        int j = ell[(size_t)row * ELLK + t];
        sidx[wave][t] = (unsigned short)j;
        sdj[wave][t]  = rsqrtf((float)(cnt[j] + 1));
    }
    __syncthreads();
    const float di = rsqrtf((float)(c + 1));
    ushort4 ys = *reinterpret_cast<const ushort4*>(Yb + (size_t)row * FF + lane * 4);
    float a0 = di * bf2f(ys.x), a1 = di * bf2f(ys.y);
    float a2 = di * bf2f(ys.z), a3 = di * bf2f(ys.w);
    for (int t = 0; t < c; ++t) {
        int j = sidx[wave][t];
        float dj = sdj[wave][t];
        ushort4 v = *reinterpret_cast<const ushort4*>(Yb + (size_t)j * FF + lane * 4);
        a0 = fmaf(dj, bf2f(v.x), a0);
        a1 = fmaf(dj, bf2f(v.y), a1);
        a2 = fmaf(dj, bf2f(v.z), a2);
        a3 = fmaf(dj, bf2f(v.w), a3);
    }
    float4 b4 = *reinterpret_cast<const float4*>(bias + lane * 4);
    float4 o;
    o.x = fmaf(di, a0, b4.x);
    o.y = fmaf(di, a1, b4.y);
    o.z = fmaf(di, a2, b4.z);
    o.w = fmaf(di, a3, b4.w);
    *reinterpret_cast<float4*>(out + (size_t)row * FF + lane * 4) = o;
}

extern "C" void kernel_launch(void* const* d_in, const int* in_sizes, int n_in,
                              void* d_out, int out_size, void* d_ws, size_t ws_size,
                              hipStream_t stream) {
    const float* A    = (const float*)d_in[0];   // [8192,8192]
    const float* X    = (const float*)d_in[1];   // [8192,256]
    const float* W    = (const float*)d_in[2];   // [256,256]
    const float* bias = (const float*)d_in[3];   // [256]
    float* out = (float*)d_out;                  // [8192,256]

    // workspace layout (~8.3 MiB):
    // Yb 4Mi | fcnt 32Ki | cnt 32Ki | bcnt 1Ki | bbuf 2Mi | ell 2Mi
    char* ws = (char*)d_ws;
    unsigned short* Yb   = (unsigned short*)(ws);
    int*            fcnt = (int*)(ws + (size_t)NN * FF * 2);
    int*            cnt  = (int*)(ws + (size_t)NN * FF * 2 + NN * 4);
    int*            bcnt = (int*)(ws + (size_t)NN * FF * 2 + NN * 8);
    unsigned int*   bbuf = (unsigned int*)(ws + (size_t)NN * FF * 2 + NN * 8 + 1024);
    unsigned short* ell  = (unsigned short*)(ws + (size_t)NN * FF * 2 + NN * 8 + 1024 + (size_t)NBUCK * BCAP * 4);

    hipMemsetAsync(bcnt, 0, NBUCK * sizeof(int), stream);

    fused_stage1<<<NGEMM + NN, 256, 0, stream>>>(A, X, W, Yb, fcnt, ell, bcnt, (unsigned int*)bbuf);
    distribute_kernel<<<NBUCK, 256, 0, stream>>>(fcnt, bcnt, bbuf, cnt, ell);
    spmm_kernel<<<NN / 4, 256, 0, stream>>>(Yb, cnt, ell, bias, out);
}

// Round 17
// 68.586 us; speedup vs baseline: 2.5859x; 2.5859x over previous
//
#include <hip/hip_runtime.h>
#include <hip/hip_bf16.h>
#include <cstdint>

// out = D^-1/2 (I+A) D^-1/2 X W + b ; N=8192, F=256, ~33 nnz/row, A symmetric.
// Stage 1 (fused, R13 exact): [MFMA GEMM Y=X@W -> bf16, 512 blocks at head] ||
//   [upper-triangle A-scan, one row per block, inline batched mirror scatter].
// Stage 2: wave-per-row gather, 4 PHASES by j>>11: each phase's Yb working set
//   is 1 MiB per XCD L2 -> gathers hit L2; each XCD reads each Yb quarter once.
// NOTE: no nontemporal hints (R4/R8/R15 regressions), no bucketing (R16).

#define NN 8192
#define FF 256
#define ELLK 128
#define BM 64
#define BN 64
#define NGEMM ((NN / BM) * (FF / BN))   // 512 gemm blocks

typedef short bf16x8 __attribute__((ext_vector_type(8)));
typedef float f32x4  __attribute__((ext_vector_type(4)));

__device__ __forceinline__ float bf2f(unsigned short u) {
    union { unsigned int i; float f; } c; c.i = ((unsigned int)u) << 16; return c.f;
}
__device__ __forceinline__ unsigned short f2bf(float f) {
    union { float f; unsigned int i; } c; c.f = f;
    unsigned int r = c.i + 0x7FFF + ((c.i >> 16) & 1);   // round-to-nearest-even
    return (unsigned short)(r >> 16);
}

__global__ __launch_bounds__(256) void fused_stage1(const float* __restrict__ A,
                                                    const float* __restrict__ X,
                                                    const float* __restrict__ W,
                                                    unsigned short* __restrict__ Yb,
                                                    int* __restrict__ cnt,
                                                    unsigned short* __restrict__ ell) {
    if (blockIdx.x < NGEMM) {
        // ------------- MFMA GEMM: Y = X @ W (bf16 in, f32 acc, bf16 out) ------
        __shared__ unsigned short Xs[64][68];
        __shared__ unsigned short Wt[64][68];
        const int bid = blockIdx.x;
        const int m0 = (bid / (FF / BN)) * BM;
        const int n0 = (bid % (FF / BN)) * BN;
        const int t  = threadIdx.x;
        const int w  = t >> 6;
        const int l  = t & 63;
        const int lm = l & 15;
        const int lk = (l >> 4) << 2;
        f32x4 acc[4] = {};
        for (int kp = 0; kp < 4; ++kp) {
            const int kbase = kp * 64;
            __syncthreads();
            {   // stage X tile 64 rows x 64 k (f32 -> bf16)
                int row = t >> 2;
                #pragma unroll
                for (int q = 0; q < 4; ++q) {
                    int kq = (t & 3) * 4 + q * 16;
                    float4 v = *reinterpret_cast<const float4*>(X + (size_t)(m0 + row) * FF + kbase + kq);
                    ushort4 b = { f2bf(v.x), f2bf(v.y), f2bf(v.z), f2bf(v.w) };
                    *reinterpret_cast<ushort4*>(&Xs[row][kq]) = b;
                }
            }
            {   // stage W^T tile: Wt[n][k] from W[k][n]
                int n4 = (t & 15) * 4;
                int kk = t >> 4;
                #pragma unroll
                for (int q = 0; q < 4; ++q) {
                    int k = kk + q * 16;
                    float4 v = *reinterpret_cast<const float4*>(W + (size_t)(kbase + k) * FF + n0 + n4);
                    Wt[n4 + 0][k] = f2bf(v.x);
                    Wt[n4 + 1][k] = f2bf(v.y);
                    Wt[n4 + 2][k] = f2bf(v.z);
                    Wt[n4 + 3][k] = f2bf(v.w);
                }
            }
            __syncthreads();
            #pragma unroll
            for (int ks = 0; ks < 2; ++ks) {
                const int k0 = ks * 32;
                union { bf16x8 v; uint2 u[2]; } af;
                af.u[0] = *reinterpret_cast<const uint2*>(&Xs[w * 16 + lm][k0 + lk]);
                af.u[1] = *reinterpret_cast<const uint2*>(&Xs[w * 16 + lm][k0 + 16 + lk]);
                #pragma unroll
                for (int f = 0; f < 4; ++f) {
                    union { bf16x8 v; uint2 u[2]; } bf;
                    bf.u[0] = *reinterpret_cast<const uint2*>(&Wt[f * 16 + lm][k0 + lk]);
                    bf.u[1] = *reinterpret_cast<const uint2*>(&Wt[f * 16 + lm][k0 + 16 + lk]);
                    acc[f] = __builtin_amdgcn_mfma_f32_16x16x32_bf16(af.v, bf.v, acc[f], 0, 0, 0);
                }
            }
        }
        #pragma unroll
        for (int f = 0; f < 4; ++f) {
            #pragma unroll
            for (int r = 0; r < 4; ++r) {
                int row = m0 + w * 16 + lk + r;
                int col = n0 + f * 16 + lm;
                Yb[(size_t)row * FF + col] = f2bf(acc[f][r]);
            }
        }
    } else {
        // ------------- upper-triangle scan, ONE row per block (R13) -----------
        __shared__ unsigned short loc[ELLK];
        __shared__ int lcnt, base;
        const int r = blockIdx.x - NGEMM;       // 0..8191
        if (threadIdx.x == 0) lcnt = 0;
        __syncthreads();
        const uint4* Arow = reinterpret_cast<const uint4*>(A + (size_t)r * NN);
        const int c0 = (r + 1) >> 2;            // first chunk that can hold j > r
        for (int c = c0 + threadIdx.x; c < NN / 4; c += 256) {
            uint4 v = Arow[c];
            if (v.x | v.y | v.z | v.w) {
                int b = c * 4;
                if (v.x && b + 0 > r) { int p = atomicAdd(&lcnt, 1); if (p < ELLK) loc[p] = (unsigned short)(b + 0); }
                if (v.y && b + 1 > r) { int p = atomicAdd(&lcnt, 1); if (p < ELLK) loc[p] = (unsigned short)(b + 1); }
                if (v.z && b + 2 > r) { int p = atomicAdd(&lcnt, 1); if (p < ELLK) loc[p] = (unsigned short)(b + 2); }
                if (v.w && b + 3 > r) { int p = atomicAdd(&lcnt, 1); if (p < ELLK) loc[p] = (unsigned short)(b + 3); }
            }
        }
        __syncthreads();
        const int n = lcnt < ELLK ? lcnt : ELLK;
        if (threadIdx.x == 0) base = atomicAdd(&cnt[r], n);   // forward reservation
        __syncthreads();
        for (int t = threadIdx.x; t < n; t += 256) {          // coalesced dump
            int p = base + t;
            if (p < ELLK) ell[(size_t)r * ELLK + p] = loc[t];
        }
        for (int t = threadIdx.x; t < n; t += 256) {          // batched mirror
            int j = loc[t];
            int q = atomicAdd(&cnt[j], 1);
            if (q < ELLK) ell[(size_t)j * ELLK + q] = (unsigned short)r;
        }
    }
}

// ---- Stage 2: wave-per-row gather, 4 phases by j-range (L2 blocking) --------
__global__ __launch_bounds__(256) void spmm_kernel(const unsigned short* __restrict__ Yb,
                                                   const int* __restrict__ cnt,
                                                   const unsigned short* __restrict__ ell,
                                                   const float* __restrict__ bias,
                                                   float* __restrict__ out) {
    const int wave = threadIdx.x >> 6;
    const int lane = threadIdx.x & 63;
    const int row = blockIdx.x * 4 + wave;
    __shared__ unsigned short sidx[4][ELLK];
    __shared__ float sdj[4][ELLK];
    int c = cnt[row];
    c = c < ELLK ? c : ELLK;
    for (int t = lane; t < c; t += 64) {
        int j = ell[(size_t)row * ELLK + t];
        sidx[wave][t] = (unsigned short)j;
        sdj[wave][t]  = rsqrtf((float)(cnt[j] + 1));
    }
    __syncthreads();
    const float di = rsqrtf((float)(c + 1));
    ushort4 ys = *reinterpret_cast<const ushort4*>(Yb + (size_t)row * FF + lane * 4);
    float a0 = di * bf2f(ys.x), a1 = di * bf2f(ys.y);
    float a2 = di * bf2f(ys.z), a3 = di * bf2f(ys.w);
    // 4 phases: only gather rows with j>>11 == ph. All co-resident blocks walk
    // phases together -> per-phase Yb working set = 1 MiB, L2-resident per XCD.
    #pragma unroll
    for (int ph = 0; ph < 4; ++ph) {
        for (int t = 0; t < c; ++t) {
            int j = sidx[wave][t];                 // wave-uniform (LDS broadcast)
            if ((j >> 11) != ph) continue;         // uniform skip, SALU-only
            float dj = sdj[wave][t];
            ushort4 v = *reinterpret_cast<const ushort4*>(Yb + (size_t)j * FF + lane * 4);
            a0 = fmaf(dj, bf2f(v.x), a0);
            a1 = fmaf(dj, bf2f(v.y), a1);
            a2 = fmaf(dj, bf2f(v.z), a2);
            a3 = fmaf(dj, bf2f(v.w), a3);
        }
    }
    float4 b4 = *reinterpret_cast<const float4*>(bias + lane * 4);
    float4 o;
    o.x = fmaf(di, a0, b4.x);
    o.y = fmaf(di, a1, b4.y);
    o.z = fmaf(di, a2, b4.z);
    o.w = fmaf(di, a3, b4.w);
    *reinterpret_cast<float4*>(out + (size_t)row * FF + lane * 4) = o;
}

extern "C" void kernel_launch(void* const* d_in, const int* in_sizes, int n_in,
                              void* d_out, int out_size, void* d_ws, size_t ws_size,
                              hipStream_t stream) {
    const float* A    = (const float*)d_in[0];   // [8192,8192]
    const float* X    = (const float*)d_in[1];   // [8192,256]
    const float* W    = (const float*)d_in[2];   // [256,256]
    const float* bias = (const float*)d_in[3];   // [256]
    float* out = (float*)d_out;                  // [8192,256]

    // workspace: Yb 4 MiB | cnt 32 KiB | ell 2 MiB
    char* ws = (char*)d_ws;
    unsigned short* Yb  = (unsigned short*)(ws);
    int*            cnt = (int*)(ws + (size_t)NN * FF * 2);
    unsigned short* ell = (unsigned short*)(ws + (size_t)NN * FF * 2 + NN * 4);

    hipMemsetAsync(cnt, 0, NN * sizeof(int), stream);

    fused_stage1<<<NGEMM + NN, 256, 0, stream>>>(A, X, W, Yb, cnt, ell);
    spmm_kernel<<<NN / 4, 256, 0, stream>>>(Yb, cnt, ell, bias, out);
}

// Round 18
// 54.313 us; speedup vs baseline: 3.2654x; 1.2628x over previous
//
#include <hip/hip_runtime.h>
#include <hip/hip_bf16.h>
#include <cstdint>

// out = D^-1/2 (I+A) D^-1/2 X W + b ; N=8192, F=256, ~33 nnz/row, A symmetric.
// Stage 1 (fused): [MFMA GEMM Y=X@W -> bf16, 512 blocks at head] ||
//   [upper-triangle A-scan, one row per block, 4x-UNROLLED load stream
//    (4 independent 16B loads in flight per wave -> latency coverage),
//    inline batched mirror scatter].
// Stage 2: wave-per-row gather (R13 exact form - measured at its BW roofline).
// NOTE: no nontemporal hints (R4/R8/R15), no bucketing (R16), no phasing (R17).

#define NN 8192
#define FF 256
#define ELLK 128
#define BM 64
#define BN 64
#define NGEMM ((NN / BM) * (FF / BN))   // 512 gemm blocks

typedef short bf16x8 __attribute__((ext_vector_type(8)));
typedef float f32x4  __attribute__((ext_vector_type(4)));

__device__ __forceinline__ float bf2f(unsigned short u) {
    union { unsigned int i; float f; } c; c.i = ((unsigned int)u) << 16; return c.f;
}
__device__ __forceinline__ unsigned short f2bf(float f) {
    union { float f; unsigned int i; } c; c.f = f;
    unsigned int r = c.i + 0x7FFF + ((c.i >> 16) & 1);   // round-to-nearest-even
    return (unsigned short)(r >> 16);
}

__global__ __launch_bounds__(256) void fused_stage1(const float* __restrict__ A,
                                                    const float* __restrict__ X,
                                                    const float* __restrict__ W,
                                                    unsigned short* __restrict__ Yb,
                                                    int* __restrict__ cnt,
                                                    unsigned short* __restrict__ ell) {
    if (blockIdx.x < NGEMM) {
        // ------------- MFMA GEMM: Y = X @ W (bf16 in, f32 acc, bf16 out) ------
        __shared__ unsigned short Xs[64][68];
        __shared__ unsigned short Wt[64][68];
        const int bid = blockIdx.x;
        const int m0 = (bid / (FF / BN)) * BM;
        const int n0 = (bid % (FF / BN)) * BN;
        const int t  = threadIdx.x;
        const int w  = t >> 6;
        const int l  = t & 63;
        const int lm = l & 15;
        const int lk = (l >> 4) << 2;
        f32x4 acc[4] = {};
        for (int kp = 0; kp < 4; ++kp) {
            const int kbase = kp * 64;
            __syncthreads();
            {   // stage X tile 64 rows x 64 k (f32 -> bf16)
                int row = t >> 2;
                #pragma unroll
                for (int q = 0; q < 4; ++q) {
                    int kq = (t & 3) * 4 + q * 16;
                    float4 v = *reinterpret_cast<const float4*>(X + (size_t)(m0 + row) * FF + kbase + kq);
                    ushort4 b = { f2bf(v.x), f2bf(v.y), f2bf(v.z), f2bf(v.w) };
                    *reinterpret_cast<ushort4*>(&Xs[row][kq]) = b;
                }
            }
            {   // stage W^T tile: Wt[n][k] from W[k][n]
                int n4 = (t & 15) * 4;
                int kk = t >> 4;
                #pragma unroll
                for (int q = 0; q < 4; ++q) {
                    int k = kk + q * 16;
                    float4 v = *reinterpret_cast<const float4*>(W + (size_t)(kbase + k) * FF + n0 + n4);
                    Wt[n4 + 0][k] = f2bf(v.x);
                    Wt[n4 + 1][k] = f2bf(v.y);
                    Wt[n4 + 2][k] = f2bf(v.z);
                    Wt[n4 + 3][k] = f2bf(v.w);
                }
            }
            __syncthreads();
            #pragma unroll
            for (int ks = 0; ks < 2; ++ks) {
                const int k0 = ks * 32;
                union { bf16x8 v; uint2 u[2]; } af;
                af.u[0] = *reinterpret_cast<const uint2*>(&Xs[w * 16 + lm][k0 + lk]);
                af.u[1] = *reinterpret_cast<const uint2*>(&Xs[w * 16 + lm][k0 + 16 + lk]);
                #pragma unroll
                for (int f = 0; f < 4; ++f) {
                    union { bf16x8 v; uint2 u[2]; } bf;
                    bf.u[0] = *reinterpret_cast<const uint2*>(&Wt[f * 16 + lm][k0 + lk]);
                    bf.u[1] = *reinterpret_cast<const uint2*>(&Wt[f * 16 + lm][k0 + 16 + lk]);
                    acc[f] = __builtin_amdgcn_mfma_f32_16x16x32_bf16(af.v, bf.v, acc[f], 0, 0, 0);
                }
            }
        }
        #pragma unroll
        for (int f = 0; f < 4; ++f) {
            #pragma unroll
            for (int r = 0; r < 4; ++r) {
                int row = m0 + w * 16 + lk + r;
                int col = n0 + f * 16 + lm;
                Yb[(size_t)row * FF + col] = f2bf(acc[f][r]);
            }
        }
    } else {
        // ------------- upper-triangle scan, ONE row per block, 4x unroll ------
        __shared__ unsigned short loc[ELLK];
        __shared__ int lcnt, base;
        const int r = blockIdx.x - NGEMM;       // 0..8191
        if (threadIdx.x == 0) lcnt = 0;
        __syncthreads();
        const uint4* Arow = reinterpret_cast<const uint4*>(A + (size_t)r * NN);
        const int c0 = (r + 1) >> 2;            // first chunk that can hold j > r

#define PROC(vv, cc)                                                                                            \
        if ((vv).x | (vv).y | (vv).z | (vv).w) {                                                                \
            int b_ = (cc) * 4;                                                                                  \
            if ((vv).x && b_ + 0 > r) { int p = atomicAdd(&lcnt, 1); if (p < ELLK) loc[p] = (unsigned short)(b_ + 0); } \
            if ((vv).y && b_ + 1 > r) { int p = atomicAdd(&lcnt, 1); if (p < ELLK) loc[p] = (unsigned short)(b_ + 1); } \
            if ((vv).z && b_ + 2 > r) { int p = atomicAdd(&lcnt, 1); if (p < ELLK) loc[p] = (unsigned short)(b_ + 2); } \
            if ((vv).w && b_ + 3 > r) { int p = atomicAdd(&lcnt, 1); if (p < ELLK) loc[p] = (unsigned short)(b_ + 3); } \
        }

        int c = c0 + threadIdx.x;
        // main loop: 4 independent 16B loads in flight before any consume
        for (; c + 768 < NN / 4; c += 1024) {
            uint4 v0 = Arow[c];
            uint4 v1 = Arow[c + 256];
            uint4 v2 = Arow[c + 512];
            uint4 v3 = Arow[c + 768];
            PROC(v0, c)
            PROC(v1, c + 256)
            PROC(v2, c + 512)
            PROC(v3, c + 768)
        }
        for (; c < NN / 4; c += 256) {          // tail
            uint4 v = Arow[c];
            PROC(v, c)
        }
#undef PROC
        __syncthreads();
        const int n = lcnt < ELLK ? lcnt : ELLK;
        if (threadIdx.x == 0) base = atomicAdd(&cnt[r], n);   // forward reservation
        __syncthreads();
        for (int t = threadIdx.x; t < n; t += 256) {          // coalesced dump
            int p = base + t;
            if (p < ELLK) ell[(size_t)r * ELLK + p] = loc[t];
        }
        for (int t = threadIdx.x; t < n; t += 256) {          // batched mirror
            int j = loc[t];
            int q = atomicAdd(&cnt[j], 1);
            if (q < ELLK) ell[(size_t)j * ELLK + q] = (unsigned short)r;
        }
    }
}

// ---- Stage 2: wave-per-row normalized aggregation over bf16 Y ---------------
__global__ __launch_bounds__(256) void spmm_kernel(const unsigned short* __restrict__ Yb,
                                                   const int* __restrict__ cnt,
                                                   const unsigned short* __restrict__ ell,
                                                   const float* __restrict__ bias,
                                                   float* __restrict__ out) {
    const int wave = threadIdx.x >> 6;
    const int lane = threadIdx.x & 63;
    const int row = blockIdx.x * 4 + wave;
    __shared__ unsigned short sidx[4][ELLK];
    __shared__ float sdj[4][ELLK];
    int c = cnt[row];
    c = c < ELLK ? c : ELLK;
    for (int t = lane; t < c; t += 64) {
        int j = ell[(size_t)row * ELLK + t];
        sidx[wave][t] = (unsigned short)j;
        sdj[wave][t]  = rsqrtf((float)(cnt[j] + 1));
    }
    __syncthreads();
    const float di = rsqrtf((float)(c + 1));
    ushort4 ys = *reinterpret_cast<const ushort4*>(Yb + (size_t)row * FF + lane * 4);
    float a0 = di * bf2f(ys.x), a1 = di * bf2f(ys.y);
    float a2 = di * bf2f(ys.z), a3 = di * bf2f(ys.w);
    for (int t = 0; t < c; ++t) {
        int j = sidx[wave][t];
        float dj = sdj[wave][t];
        ushort4 v = *reinterpret_cast<const ushort4*>(Yb + (size_t)j * FF + lane * 4);
        a0 = fmaf(dj, bf2f(v.x), a0);
        a1 = fmaf(dj, bf2f(v.y), a1);
        a2 = fmaf(dj, bf2f(v.z), a2);
        a3 = fmaf(dj, bf2f(v.w), a3);
    }
    float4 b4 = *reinterpret_cast<const float4*>(bias + lane * 4);
    float4 o;
    o.x = fmaf(di, a0, b4.x);
    o.y = fmaf(di, a1, b4.y);
    o.z = fmaf(di, a2, b4.z);
    o.w = fmaf(di, a3, b4.w);
    *reinterpret_cast<float4*>(out + (size_t)row * FF + lane * 4) = o;
}

extern "C" void kernel_launch(void* const* d_in, const int* in_sizes, int n_in,
                              void* d_out, int out_size, void* d_ws, size_t ws_size,
                              hipStream_t stream) {
    const float* A    = (const float*)d_in[0];   // [8192,8192]
    const float* X    = (const float*)d_in[1];   // [8192,256]
    const float* W    = (const float*)d_in[2];   // [256,256]
    const float* bias = (const float*)d_in[3];   // [256]
    float* out = (float*)d_out;                  // [8192,256]

    // workspace: Yb 4 MiB | cnt 32 KiB | ell 2 MiB
    char* ws = (char*)d_ws;
    unsigned short* Yb  = (unsigned short*)(ws);
    int*            cnt = (int*)(ws + (size_t)NN * FF * 2);
    unsigned short* ell = (unsigned short*)(ws + (size_t)NN * FF * 2 + NN * 4);

    hipMemsetAsync(cnt, 0, NN * sizeof(int), stream);

    fused_stage1<<<NGEMM + NN, 256, 0, stream>>>(A, X, W, Yb, cnt, ell);
    spmm_kernel<<<NN / 4, 256, 0, stream>>>(Yb, cnt, ell, bias, out);
}